// Round 5
// baseline (199.645 us; speedup 1.0000x reference)
//
#include <hip/hip_runtime.h>

#define NPIX (128 * 128)
#define CH 64
#define RMID 16
#define KK 9
#define TOTPIX (8 * NPIX)        // 131072

// ---------------- K1: conv1 + PReLU -> t_ws ----------------
// t_ws layout: [r][G]  (r<16, G = global pixel id) -> coalesced stores/loads.
__global__ __launch_bounds__(256, 8) void conv1_kernel(
    const float* __restrict__ x,
    const float* __restrict__ w1,
    const float* __restrict__ b1,
    const float* __restrict__ prelu_a,
    float* __restrict__ t_ws)
{
    const int G = blockIdx.x * 256 + threadIdx.x;    // 0..131071
    const int bq = G >> 14;
    const int p  = G & (NPIX - 1);
    const float* xp = x + (size_t)bq * CH * NPIX + p;

    float t[RMID];
#pragma unroll
    for (int r = 0; r < RMID; ++r) t[r] = b1[r];

#pragma unroll 8
    for (int c = 0; c < CH; ++c) {
        const float xv = xp[(size_t)c * NPIX];
#pragma unroll
        for (int r = 0; r < RMID; ++r)
            t[r] = fmaf(w1[r * CH + c], xv, t[r]);   // w1 uniform -> s_load
    }
    const float a = prelu_a[0];
#pragma unroll
    for (int r = 0; r < RMID; ++r) {
        const float v = t[r];
        t_ws[r * TOTPIX + G] = (v >= 0.f) ? v : a * v;
    }
}

// ---------------- K2: conv2 (weight gen) + involution ----------------
// blockIdx.x: batch*row-pair (512), blockIdx.y: group-quad gq (8) -> groups
// 4gq..4gq+3 are BLOCK-uniform => scalar plane bases. 256 thr = 2 rows x 128 px.
// Interior rows: immediate -512/0/+512 row offsets; border: clamped + masked.
__global__ __launch_bounds__(256, 8) void invol_kernel(
    const float* __restrict__ x,
    const float* __restrict__ t_ws,
    const float* __restrict__ w2,
    const float* __restrict__ b2,
    float* __restrict__ out)
{
    const int px   = threadIdx.x & 127;
    const int rsub = threadIdx.x >> 7;         // 0..1 (wave-pair uniform)
    const int blk  = blockIdx.x;               // 0..511
    const int bq   = blk >> 6;
    const int hq   = 2 * (blk & 63) + rsub;
    const int p    = hq * 128 + px;
    const int gq   = blockIdx.y;               // group-quad

    // t fragment: 16 coalesced loads (L2-resident)
    const int G = (bq << 14) + p;
    float tr[RMID];
#pragma unroll
    for (int r = 0; r < RMID; ++r) tr[r] = t_ws[r * TOTPIX + G];

    // per-lane clamped column byte-offsets + masks
    const int   pb   = 4 * p;
    const int   cneg = (px > 0)   ? pb - 4 : pb;
    const int   cpos = (px < 127) ? pb + 4 : pb;
    const float mneg = (px > 0)   ? 1.f : 0.f;
    const float mpos = (px < 127) ? 1.f : 0.f;

    // row offsets (wave-uniform; interior blocks get immediates after inlining)
    const bool interior = (hq >= 1) && (hq <= 126);
    const int   ro0 = interior ? -512 : ((hq > 0)   ? -512 : 0);
    const int   ro2 = interior ?  512 : ((hq < 127) ?  512 : 0);
    const float rm0 = (hq > 0)   ? 1.f : 0.f;
    const float rm2 = (hq < 127) ? 1.f : 0.f;

    const char* xbc = (const char*)(x   + (size_t)bq * CH * NPIX);
    char*       obc = (char*)      (out + (size_t)bq * CH * NPIX);

#pragma unroll 2
    for (int gi = 0; gi < 4; ++gi) {
        const int g = 4 * gq + gi;                        // block-uniform
        const char* c0 = xbc + (size_t)(2 * g) * NPIX * 4;
        const char* c1 = c0 + NPIX * 4;

        // -- 18 stencil loads, batched --
        float p0[KK], p1[KK];
#pragma unroll
        for (int i = 0; i < 3; ++i) {
            const int ro = (i == 0) ? ro0 : (i == 2) ? ro2 : 0;
#pragma unroll
            for (int j = 0; j < 3; ++j) {
                const int k    = i * 3 + j;
                const int voff = (j == 0) ? cneg : (j == 2) ? cpos : pb;
                p0[k] = *(const float*)(c0 + (size_t)(voff + ro));
                p1[k] = *(const float*)(c1 + (size_t)(voff + ro));
            }
        }

        // -- conv2: 9 weights from tr[16] (covers the load latency) --
        float wg[KK];
#pragma unroll
        for (int k = 0; k < KK; ++k) {
            float acc = b2[g * KK + k];
            const float* w2r = w2 + (g * KK + k) * RMID;   // uniform -> s_load
#pragma unroll
            for (int r = 0; r < RMID; ++r)
                acc = fmaf(w2r[r], tr[r], acc);
            wg[k] = acc;
        }
        // fold border masks (interior: rm=1 -> 6 column mults)
        wg[0] *= mneg * rm0;  wg[1] *= rm0;  wg[2] *= mpos * rm0;
        wg[3] *= mneg;                       wg[5] *= mpos;
        wg[6] *= mneg * rm2;  wg[7] *= rm2;  wg[8] *= mpos * rm2;

        // -- combine + store --
        float o0 = 0.f, o1 = 0.f;
#pragma unroll
        for (int k = 0; k < KK; ++k) {
            o0 = fmaf(wg[k], p0[k], o0);
            o1 = fmaf(wg[k], p1[k], o1);
        }
        *(float*)(obc + (size_t)(2 * g) * NPIX * 4 + pb)     = o0;
        *(float*)(obc + (size_t)(2 * g + 1) * NPIX * 4 + pb) = o1;
    }
}

extern "C" void kernel_launch(void* const* d_in, const int* in_sizes, int n_in,
                              void* d_out, int out_size, void* d_ws, size_t ws_size,
                              hipStream_t stream)
{
    const float* x  = (const float*)d_in[0];
    const float* w1 = (const float*)d_in[1];
    const float* b1 = (const float*)d_in[2];
    const float* pa = (const float*)d_in[3];
    const float* w2 = (const float*)d_in[4];
    const float* b2 = (const float*)d_in[5];
    float* out  = (float*)d_out;
    float* t_ws = (float*)d_ws;              // 16 * 131072 * 4 B = 8.4 MB

    hipLaunchKernelGGL(conv1_kernel, dim3(TOTPIX / 256), dim3(256), 0, stream,
                       x, w1, b1, pa, t_ws);
    hipLaunchKernelGGL(invol_kernel, dim3(512, 8), dim3(256), 0, stream,
                       x, t_ws, w2, b2, out);
}

// Round 6
// 145.224 us; speedup vs baseline: 1.3747x; 1.3747x over previous
//
#include <hip/hip_runtime.h>

#define NPIX (128 * 128)
#define CH 64
#define RMID 16
#define KK 9
#define TOTPIX (8 * NPIX)        // 131072

// ---------------- K1: conv1 + PReLU -> t_ws ----------------
// t_ws layout: [r][G]  (r<16, G = global pixel id) -> coalesced.
// All 64 x loads issued up-front (single vmcnt drain), then 1024 FMA.
__global__ __launch_bounds__(256) void conv1_kernel(
    const float* __restrict__ x,
    const float* __restrict__ w1,
    const float* __restrict__ b1,
    const float* __restrict__ prelu_a,
    float* __restrict__ t_ws)
{
    const int G  = blockIdx.x * 256 + threadIdx.x;   // 0..131071
    const int bq = G >> 14;
    const int p  = G & (NPIX - 1);
    const float* xp = x + (size_t)bq * CH * NPIX + p;

    float xv[CH];
#pragma unroll
    for (int c = 0; c < CH; ++c) xv[c] = xp[(size_t)c * NPIX];  // 64 loads in flight

    float t[RMID];
#pragma unroll
    for (int r = 0; r < RMID; ++r) t[r] = b1[r];

#pragma unroll
    for (int c = 0; c < CH; ++c) {
#pragma unroll
        for (int r = 0; r < RMID; ++r)
            t[r] = fmaf(w1[r * CH + c], xv[c], t[r]);   // w1 uniform -> s_load
    }
    const float a = prelu_a[0];
#pragma unroll
    for (int r = 0; r < RMID; ++r) {
        const float v = t[r];
        t_ws[r * TOTPIX + G] = (v >= 0.f) ? v : a * v;
    }
}

// ---------------- K2: conv2 (weight gen) + involution ----------------
// 1D grid, XCD-pinned: bq = L&7 (block->XCD ~ L%8), gq = (L>>3)&7 fastest
// (the 8 group-quad slices of a strip are consecutive blocks on one XCD ->
// t-strip fetched once, hit 7x in that XCD's L2), strip = L>>6.
// 256 thr = 2 rows x 128 px; groups 4gq..4gq+3 block-uniform -> scalar bases.
// out stores nontemporal: no write-allocate, no L2 pollution.
__global__ __launch_bounds__(256, 8) void invol_kernel(
    const float* __restrict__ x,
    const float* __restrict__ t_ws,
    const float* __restrict__ w2,
    const float* __restrict__ b2,
    float* __restrict__ out)
{
    const int px   = threadIdx.x & 127;
    const int rsub = threadIdx.x >> 7;          // 0..1

    const int L     = blockIdx.x;               // 0..4095
    const int bq    = L & 7;                    // batch == XCD pin
    const int gq    = (L >> 3) & 7;             // group-quad (fastest per XCD)
    const int strip = L >> 6;                   // 0..63 row-pair

    const int hq = 2 * strip + rsub;
    const int p  = hq * 128 + px;

    // t fragment: 16 coalesced loads (L2-resident after swizzle)
    const int G = (bq << 14) + p;
    float tr[RMID];
#pragma unroll
    for (int r = 0; r < RMID; ++r) tr[r] = t_ws[r * TOTPIX + G];

    // per-lane clamped column byte-offsets + masks
    const int   pb   = 4 * p;
    const int   cneg = (px > 0)   ? pb - 4 : pb;
    const int   cpos = (px < 127) ? pb + 4 : pb;
    const float mneg = (px > 0)   ? 1.f : 0.f;
    const float mpos = (px < 127) ? 1.f : 0.f;

    // row offsets (wave-uniform)
    const int   ro0 = (hq > 0)   ? -512 : 0;
    const int   ro2 = (hq < 127) ?  512 : 0;
    const float rm0 = (hq > 0)   ? 1.f : 0.f;
    const float rm2 = (hq < 127) ? 1.f : 0.f;

    const char* xbc = (const char*)(x   + (size_t)bq * CH * NPIX);
    char*       obc = (char*)      (out + (size_t)bq * CH * NPIX);

#pragma unroll 2
    for (int gi = 0; gi < 4; ++gi) {
        const int g = 4 * gq + gi;                        // block-uniform
        const char* c0 = xbc + (size_t)(2 * g) * NPIX * 4;
        const char* c1 = c0 + NPIX * 4;

        // -- 18 stencil loads, batched --
        float p0[KK], p1[KK];
#pragma unroll
        for (int i = 0; i < 3; ++i) {
            const int ro = (i == 0) ? ro0 : (i == 2) ? ro2 : 0;
#pragma unroll
            for (int j = 0; j < 3; ++j) {
                const int k    = i * 3 + j;
                const int voff = (j == 0) ? cneg : (j == 2) ? cpos : pb;
                p0[k] = *(const float*)(c0 + (size_t)(voff + ro));
                p1[k] = *(const float*)(c1 + (size_t)(voff + ro));
            }
        }

        // -- conv2: 9 weights from tr[16] (covers the load latency) --
        float wg[KK];
#pragma unroll
        for (int k = 0; k < KK; ++k) {
            float acc = b2[g * KK + k];
            const float* w2r = w2 + (g * KK + k) * RMID;   // uniform -> s_load
#pragma unroll
            for (int r = 0; r < RMID; ++r)
                acc = fmaf(w2r[r], tr[r], acc);
            wg[k] = acc;
        }
        // fold border masks
        wg[0] *= mneg * rm0;  wg[1] *= rm0;  wg[2] *= mpos * rm0;
        wg[3] *= mneg;                       wg[5] *= mpos;
        wg[6] *= mneg * rm2;  wg[7] *= rm2;  wg[8] *= mpos * rm2;

        // -- combine + nontemporal store --
        float o0 = 0.f, o1 = 0.f;
#pragma unroll
        for (int k = 0; k < KK; ++k) {
            o0 = fmaf(wg[k], p0[k], o0);
            o1 = fmaf(wg[k], p1[k], o1);
        }
        __builtin_nontemporal_store(o0, (float*)(obc + (size_t)(2 * g)     * NPIX * 4 + pb));
        __builtin_nontemporal_store(o1, (float*)(obc + (size_t)(2 * g + 1) * NPIX * 4 + pb));
    }
}

extern "C" void kernel_launch(void* const* d_in, const int* in_sizes, int n_in,
                              void* d_out, int out_size, void* d_ws, size_t ws_size,
                              hipStream_t stream)
{
    const float* x  = (const float*)d_in[0];
    const float* w1 = (const float*)d_in[1];
    const float* b1 = (const float*)d_in[2];
    const float* pa = (const float*)d_in[3];
    const float* w2 = (const float*)d_in[4];
    const float* b2 = (const float*)d_in[5];
    float* out  = (float*)d_out;
    float* t_ws = (float*)d_ws;              // 16 * 131072 * 4 B = 8.4 MB

    hipLaunchKernelGGL(conv1_kernel, dim3(TOTPIX / 256), dim3(256), 0, stream,
                       x, w1, b1, pa, t_ws);
    hipLaunchKernelGGL(invol_kernel, dim3(8 * 8 * 64), dim3(256), 0, stream,
                       x, t_ws, w2, b2, out);
}